// Round 1
// baseline (772.346 us; speedup 1.0000x reference)
//
#include <hip/hip_runtime.h>
#include <math.h>

#define WSZ 11
#define PAD 5
#define TX 32
#define TY 32
#define IX (TX + 2*PAD)   // 42
#define IY (TY + 2*PAD)   // 42
#define SSTR (IX + 1)     // 43, pad to break power-of-2 stride

struct W11 { float w[WSZ]; };

__global__ __launch_bounds__(256) void ssim_l1_kernel(
    const float* __restrict__ pred, const float* __restrict__ targ,
    int H, int W, W11 wt, double* __restrict__ acc)
{
    __shared__ float sP[IY][SSTR];
    __shared__ float sT[IY][SSTR];
    __shared__ float sH[5][IY][TX];   // h-conv of p, t, p^2, t^2, p*t

    const int c   = blockIdx.z;
    const int gx0 = blockIdx.x * TX;
    const int gy0 = blockIdx.y * TY;
    const size_t plane = (size_t)H * W;
    const float* p = pred + (size_t)c * plane;
    const float* t = targ + (size_t)c * plane;

    // ---- stage input tile (+halo) with zero padding ----
    for (int i = threadIdx.x; i < IY * IX; i += 256) {
        int iy = i / IX, ix = i % IX;
        int gy = gy0 + iy - PAD, gx = gx0 + ix - PAD;
        float pv = 0.f, tv = 0.f;
        if (gy >= 0 && gy < H && gx >= 0 && gx < W) {
            size_t idx = (size_t)gy * W + gx;
            pv = p[idx];
            tv = t[idx];
        }
        sP[iy][ix] = pv;
        sT[iy][ix] = tv;
    }
    __syncthreads();

    // ---- horizontal 11-tap pass (5 quantities) ----
    for (int i = threadIdx.x; i < IY * TX; i += 256) {
        int iy = i / TX, ox = i % TX;
        float hp = 0.f, ht = 0.f, hpp = 0.f, htt = 0.f, hpt = 0.f;
        #pragma unroll
        for (int k = 0; k < WSZ; ++k) {
            float wv = wt.w[k];
            float pv = sP[iy][ox + k];
            float tv = sT[iy][ox + k];
            hp  += wv * pv;
            ht  += wv * tv;
            hpp += wv * pv * pv;
            htt += wv * tv * tv;
            hpt += wv * pv * tv;
        }
        sH[0][iy][ox] = hp;
        sH[1][iy][ox] = ht;
        sH[2][iy][ox] = hpp;
        sH[3][iy][ox] = htt;
        sH[4][iy][ox] = hpt;
    }
    __syncthreads();

    // ---- vertical 11-tap pass + SSIM + L1 ----
    const float C1v = 0.0001f;   // 0.01^2
    const float C2v = 0.0009f;   // 0.03^2
    float ssim_acc = 0.f, l1_acc = 0.f;
    for (int i = threadIdx.x; i < TY * TX; i += 256) {
        int oy = i / TX, ox = i % TX;
        int gy = gy0 + oy, gx = gx0 + ox;
        if (gy < H && gx < W) {
            float mu1 = 0.f, mu2 = 0.f, spp = 0.f, stt = 0.f, spt = 0.f;
            #pragma unroll
            for (int k = 0; k < WSZ; ++k) {
                float wv = wt.w[k];
                mu1 += wv * sH[0][oy + k][ox];
                mu2 += wv * sH[1][oy + k][ox];
                spp += wv * sH[2][oy + k][ox];
                stt += wv * sH[3][oy + k][ox];
                spt += wv * sH[4][oy + k][ox];
            }
            float mu1s = mu1 * mu1;
            float mu2s = mu2 * mu2;
            float m12  = mu1 * mu2;
            float s1   = spp - mu1s;
            float s2   = stt - mu2s;
            float s12  = spt - m12;
            float num = (2.f * m12 + C1v) * (2.f * s12 + C2v);
            float den = (mu1s + mu2s + C1v) * (s1 + s2 + C2v);
            ssim_acc += num / den;
            float pv = sP[oy + PAD][ox + PAD];
            float tv = sT[oy + PAD][ox + PAD];
            l1_acc += fabsf(pv - tv);
        }
    }

    // ---- block reduction: wave shuffle, then LDS across 4 waves ----
    #pragma unroll
    for (int off = 32; off > 0; off >>= 1) {
        ssim_acc += __shfl_down(ssim_acc, off, 64);
        l1_acc   += __shfl_down(l1_acc,   off, 64);
    }
    __shared__ float red[2][4];
    int lane = threadIdx.x & 63;
    int wid  = threadIdx.x >> 6;
    if (lane == 0) { red[0][wid] = ssim_acc; red[1][wid] = l1_acc; }
    __syncthreads();
    if (threadIdx.x == 0) {
        float s = red[0][0] + red[0][1] + red[0][2] + red[0][3];
        float l = red[1][0] + red[1][1] + red[1][2] + red[1][3];
        atomicAdd(&acc[0], (double)s);
        atomicAdd(&acc[1], (double)l);
    }
}

__global__ void finalize_kernel(const double* __restrict__ acc,
                                float* __restrict__ out, double invN)
{
    double ssim_mean = acc[0] * invN;
    double l1_mean   = acc[1] * invN;
    // (1 - lambda) * l1 + lambda * (1 - ssim), lambda = 0.2
    out[0] = (float)(0.8 * l1_mean + 0.2 * (1.0 - ssim_mean));
}

extern "C" void kernel_launch(void* const* d_in, const int* in_sizes, int n_in,
                              void* d_out, int out_size, void* d_ws, size_t ws_size,
                              hipStream_t stream)
{
    const float* pred = (const float*)d_in[0];
    const float* targ = (const float*)d_in[1];
    float* out = (float*)d_out;
    double* acc = (double*)d_ws;

    const int C = 3, H = 2160, W = 3840;

    // zero the two double accumulators (ws is poisoned to 0xAA each launch)
    hipMemsetAsync(acc, 0, 2 * sizeof(double), stream);

    // Gaussian window, computed to match jnp f32 semantics closely enough
    W11 wt;
    double g[WSZ], s = 0.0;
    for (int i = 0; i < WSZ; ++i) {
        double d = (double)i - (WSZ / 2);
        g[i] = exp(-(d * d) / (2.0 * 1.5 * 1.5));
        s += g[i];
    }
    for (int i = 0; i < WSZ; ++i) wt.w[i] = (float)(g[i] / s);

    dim3 grid((W + TX - 1) / TX, (H + TY - 1) / TY, C);
    ssim_l1_kernel<<<grid, 256, 0, stream>>>(pred, targ, H, W, wt, acc);

    double invN = 1.0 / ((double)C * (double)H * (double)W);
    finalize_kernel<<<1, 1, 0, stream>>>(acc, out, invN);
}

// Round 2
// 551.244 us; speedup vs baseline: 1.4011x; 1.4011x over previous
//
#include <hip/hip_runtime.h>
#include <math.h>

#define WSZ 11
#define PAD 5
#define TX 32
#define TY 48
#define IY (TY + 2*PAD)      // 58
#define RX 8
#define NLX (TX / RX)        // 4 threads per row in h-pass
#define SSTR (TX + 1)        // 33: odd stride -> <=2-way bank aliasing
#define RY 6                 // output rows per thread in v-pass
#define SEG (RX + 2*PAD)     // 18 floats per h-pass thread segment

struct W11 { float w[WSZ]; };

__global__ __launch_bounds__(256, 4) void ssim_l1_kernel(
    const float* __restrict__ pred, const float* __restrict__ targ,
    W11 wt, double* __restrict__ acc)
{
    constexpr int H = 2160, W = 3840;
    __shared__ float sH[5][IY][SSTR];   // h-conv of p, t, p^2, t^2, p*t

    const int c   = blockIdx.z;
    const int gx0 = blockIdx.x * TX;
    const int gy0 = blockIdx.y * TY;
    const size_t plane = (size_t)H * W;
    const float* p = pred + (size_t)c * plane;
    const float* t = targ + (size_t)c * plane;

    const int tid = threadIdx.x;
    float l1_acc = 0.f;

    // ================= Phase A: horizontal 11-tap, global -> LDS ===========
    // thread -> (row r in [0,IY), x-chunk lx in [0,4)); threads 232..255 idle
    {
        const int r  = tid >> 2;
        const int lx = tid & 3;
        if (r < IY) {
            const int gy  = gy0 + r - PAD;
            const int gxs = gx0 + lx * RX - PAD;      // segment start (SEG floats)
            const bool rowok = (gy >= 0) && (gy < H);

            float pv[SEG], tv[SEG];
            if (rowok && blockIdx.x >= 1 && blockIdx.x <= (W / TX) - 2) {
                // fast path: gxs-3 = gx0 + lx*8 - 8 is 32B-aligned
                const float4* p4 = (const float4*)(p + (size_t)gy * W + (gxs - 3));
                const float4* t4 = (const float4*)(t + (size_t)gy * W + (gxs - 3));
                float pb[24], tb[24];
                #pragma unroll
                for (int i = 0; i < 6; ++i) {
                    float4 a = p4[i];
                    pb[4*i+0] = a.x; pb[4*i+1] = a.y; pb[4*i+2] = a.z; pb[4*i+3] = a.w;
                    float4 b = t4[i];
                    tb[4*i+0] = b.x; tb[4*i+1] = b.y; tb[4*i+2] = b.z; tb[4*i+3] = b.w;
                }
                #pragma unroll
                for (int e = 0; e < SEG; ++e) { pv[e] = pb[e+3]; tv[e] = tb[e+3]; }
            } else if (rowok) {
                // x-edge block: guarded scalar loads
                const size_t rowoff = (size_t)gy * W;
                #pragma unroll
                for (int e = 0; e < SEG; ++e) {
                    int gx = gxs + e;
                    bool ok = (gx >= 0) && (gx < W);
                    pv[e] = ok ? p[rowoff + gx] : 0.f;
                    tv[e] = ok ? t[rowoff + gx] : 0.f;
                }
            } else {
                #pragma unroll
                for (int e = 0; e < SEG; ++e) { pv[e] = 0.f; tv[e] = 0.f; }
            }

            float hp[RX], ht[RX], hpp[RX], htt[RX], hpt[RX];
            #pragma unroll
            for (int j = 0; j < RX; ++j) {
                hp[j] = 0.f; ht[j] = 0.f; hpp[j] = 0.f; htt[j] = 0.f; hpt[j] = 0.f;
            }
            #pragma unroll
            for (int e = 0; e < SEG; ++e) {
                float pe = pv[e], te = tv[e];
                float pp = pe * pe, tt = te * te, pt = pe * te;
                #pragma unroll
                for (int j = 0; j < RX; ++j) {
                    constexpr int lo = 0;
                    int k = e - j;
                    if (k >= lo && k < WSZ) {
                        float wv = wt.w[k];
                        hp[j]  += wv * pe;
                        ht[j]  += wv * te;
                        hpp[j] += wv * pp;
                        htt[j] += wv * tt;
                        hpt[j] += wv * pt;
                    }
                }
            }
            const int xb = lx * RX;
            #pragma unroll
            for (int j = 0; j < RX; ++j) {
                sH[0][r][xb + j] = hp[j];
                sH[1][r][xb + j] = ht[j];
                sH[2][r][xb + j] = hpp[j];
                sH[3][r][xb + j] = htt[j];
                sH[4][r][xb + j] = hpt[j];
            }
            // L1 over the pixels this block owns (each staged exactly once):
            // owned rows r in [PAD, PAD+TY), owned x = segment elems [PAD, PAD+RX)
            if (r >= PAD && r < PAD + TY) {
                #pragma unroll
                for (int e = PAD; e < PAD + RX; ++e)
                    l1_acc += fabsf(pv[e] - tv[e]);
            }
        }
    }
    __syncthreads();

    // ================= Phase B: vertical 11-tap + SSIM ======================
    const float C1v = 0.0001f, C2v = 0.0009f;
    float ssim_acc = 0.f;
    {
        const int ox  = tid & 31;
        const int oy0 = (tid >> 5) * RY;
        float v[5][RY + 2 * PAD];           // 16-row window x 5 quantities
        #pragma unroll
        for (int k = 0; k < RY + 2 * PAD; ++k) {
            #pragma unroll
            for (int q = 0; q < 5; ++q)
                v[q][k] = sH[q][oy0 + k][ox];
        }
        #pragma unroll
        for (int j = 0; j < RY; ++j) {
            float mu1 = 0.f, mu2 = 0.f, spp = 0.f, stt = 0.f, spt = 0.f;
            #pragma unroll
            for (int k = 0; k < WSZ; ++k) {
                float wv = wt.w[k];
                mu1 += wv * v[0][j + k];
                mu2 += wv * v[1][j + k];
                spp += wv * v[2][j + k];
                stt += wv * v[3][j + k];
                spt += wv * v[4][j + k];
            }
            float mu1s = mu1 * mu1;
            float mu2s = mu2 * mu2;
            float m12  = mu1 * mu2;
            float num = (2.f * m12 + C1v) * (2.f * (spt - m12) + C2v);
            float den = (mu1s + mu2s + C1v) * ((spp - mu1s) + (stt - mu2s) + C2v);
            ssim_acc += num / den;
        }
    }

    // ================= block reduction -> global double atomics =============
    #pragma unroll
    for (int off = 32; off > 0; off >>= 1) {
        ssim_acc += __shfl_down(ssim_acc, off, 64);
        l1_acc   += __shfl_down(l1_acc,   off, 64);
    }
    __shared__ float red[2][4];
    int lane = tid & 63;
    int wid  = tid >> 6;
    if (lane == 0) { red[0][wid] = ssim_acc; red[1][wid] = l1_acc; }
    __syncthreads();
    if (tid == 0) {
        float s = red[0][0] + red[0][1] + red[0][2] + red[0][3];
        float l = red[1][0] + red[1][1] + red[1][2] + red[1][3];
        atomicAdd(&acc[0], (double)s);
        atomicAdd(&acc[1], (double)l);
    }
}

__global__ void finalize_kernel(const double* __restrict__ acc,
                                float* __restrict__ out, double invN)
{
    double ssim_mean = acc[0] * invN;
    double l1_mean   = acc[1] * invN;
    out[0] = (float)(0.8 * l1_mean + 0.2 * (1.0 - ssim_mean));
}

extern "C" void kernel_launch(void* const* d_in, const int* in_sizes, int n_in,
                              void* d_out, int out_size, void* d_ws, size_t ws_size,
                              hipStream_t stream)
{
    const float* pred = (const float*)d_in[0];
    const float* targ = (const float*)d_in[1];
    float* out = (float*)d_out;
    double* acc = (double*)d_ws;

    const int C = 3, H = 2160, W = 3840;

    hipMemsetAsync(acc, 0, 2 * sizeof(double), stream);

    W11 wt;
    double g[WSZ], s = 0.0;
    for (int i = 0; i < WSZ; ++i) {
        double d = (double)i - (WSZ / 2);
        g[i] = exp(-(d * d) / (2.0 * 1.5 * 1.5));
        s += g[i];
    }
    for (int i = 0; i < WSZ; ++i) wt.w[i] = (float)(g[i] / s);

    dim3 grid(W / TX, H / TY, C);   // 120 x 45 x 3
    ssim_l1_kernel<<<grid, 256, 0, stream>>>(pred, targ, wt, acc);

    double invN = 1.0 / ((double)C * (double)H * (double)W);
    finalize_kernel<<<1, 1, 0, stream>>>(acc, out, invN);
}

// Round 3
// 544.783 us; speedup vs baseline: 1.4177x; 1.0119x over previous
//
#include <hip/hip_runtime.h>
#include <math.h>

#define WSZ 11
#define PAD 5
#define TX 32
#define TY 48
#define IY (TY + 2*PAD)      // 58
#define RX 8
#define SSTR (TX + 1)        // 33: odd stride -> <=2-way bank aliasing (free)
#define RY 6                 // output rows per thread in v-pass
#define SEG (RX + 2*PAD)     // 18 floats per h-pass thread segment

struct W11 { float w[WSZ]; };

__global__ __launch_bounds__(256, 4) void ssim_l1_kernel(
    const float* __restrict__ pred, const float* __restrict__ targ,
    W11 wt, double* __restrict__ acc)
{
    constexpr int H = 2160, W = 3840;
    __shared__ float sH[5][IY][SSTR];   // h-conv of p, t, p^2, t^2, p*t

    const int c   = blockIdx.z;
    const int gx0 = blockIdx.x * TX;
    const int gy0 = blockIdx.y * TY;
    const size_t plane = (size_t)H * W;
    const float* p = pred + (size_t)c * plane;
    const float* t = targ + (size_t)c * plane;

    const int tid = threadIdx.x;
    float l1_acc = 0.f;

    // ================= Phase A: horizontal 11-tap, global -> LDS ===========
    // thread -> (row r in [0,IY), x-chunk lx in [0,4)); threads 232..255 idle
    {
        const int r  = tid >> 2;
        const int lx = tid & 3;
        if (r < IY) {
            const int gy  = gy0 + r - PAD;
            const int gxs = gx0 + lx * RX - PAD;      // segment start (SEG floats)
            const bool rowok = (gy >= 0) && (gy < H);

            float pv[SEG], tv[SEG];
            if (rowok && blockIdx.x >= 1 && blockIdx.x <= (W / TX) - 2) {
                // fast path: gxs-3 = gx0 + lx*8 - 8 is 32B-aligned
                const float4* p4 = (const float4*)(p + (size_t)gy * W + (gxs - 3));
                const float4* t4 = (const float4*)(t + (size_t)gy * W + (gxs - 3));
                float pb[24], tb[24];
                #pragma unroll
                for (int i = 0; i < 6; ++i) {
                    float4 a = p4[i];
                    pb[4*i+0] = a.x; pb[4*i+1] = a.y; pb[4*i+2] = a.z; pb[4*i+3] = a.w;
                    float4 b = t4[i];
                    tb[4*i+0] = b.x; tb[4*i+1] = b.y; tb[4*i+2] = b.z; tb[4*i+3] = b.w;
                }
                #pragma unroll
                for (int e = 0; e < SEG; ++e) { pv[e] = pb[e+3]; tv[e] = tb[e+3]; }
            } else if (rowok) {
                // x-edge block: guarded scalar loads
                const size_t rowoff = (size_t)gy * W;
                #pragma unroll
                for (int e = 0; e < SEG; ++e) {
                    int gx = gxs + e;
                    bool ok = (gx >= 0) && (gx < W);
                    pv[e] = ok ? p[rowoff + gx] : 0.f;
                    tv[e] = ok ? t[rowoff + gx] : 0.f;
                }
            } else {
                #pragma unroll
                for (int e = 0; e < SEG; ++e) { pv[e] = 0.f; tv[e] = 0.f; }
            }

            // e-outer / j-inner: only the 40 accumulators stay live
            float hp[RX], ht[RX], hpp[RX], htt[RX], hpt[RX];
            #pragma unroll
            for (int j = 0; j < RX; ++j) {
                hp[j] = 0.f; ht[j] = 0.f; hpp[j] = 0.f; htt[j] = 0.f; hpt[j] = 0.f;
            }
            #pragma unroll
            for (int e = 0; e < SEG; ++e) {
                float pe = pv[e], te = tv[e];
                float pp = pe * pe, tt = te * te, pt = pe * te;
                #pragma unroll
                for (int j = 0; j < RX; ++j) {
                    int k = e - j;
                    if (k >= 0 && k < WSZ) {
                        float wv = wt.w[k];
                        hp[j]  += wv * pe;
                        ht[j]  += wv * te;
                        hpp[j] += wv * pp;
                        htt[j] += wv * tt;
                        hpt[j] += wv * pt;
                    }
                }
            }
            const int xb = lx * RX;
            #pragma unroll
            for (int j = 0; j < RX; ++j) {
                sH[0][r][xb + j] = hp[j];
                sH[1][r][xb + j] = ht[j];
                sH[2][r][xb + j] = hpp[j];
                sH[3][r][xb + j] = htt[j];
                sH[4][r][xb + j] = hpt[j];
            }
            // L1 over the pixels this block owns (each staged exactly once)
            if (r >= PAD && r < PAD + TY) {
                #pragma unroll
                for (int e = PAD; e < PAD + RX; ++e)
                    l1_acc += fabsf(pv[e] - tv[e]);
            }
        }
    }
    __syncthreads();

    // ================= Phase B: vertical 11-tap + SSIM ======================
    // k-outer / j-inner: each LDS value read exactly once, 30 accumulators.
    const float C1v = 0.0001f, C2v = 0.0009f;
    float ssim_acc = 0.f;
    {
        const int ox  = tid & 31;
        const int oy0 = (tid >> 5) * RY;
        float mu1[RY], mu2[RY], spp[RY], stt[RY], spt[RY];
        #pragma unroll
        for (int j = 0; j < RY; ++j) {
            mu1[j] = 0.f; mu2[j] = 0.f; spp[j] = 0.f; stt[j] = 0.f; spt[j] = 0.f;
        }
        #pragma unroll
        for (int k = 0; k < RY + 2 * PAD; ++k) {
            float a0 = sH[0][oy0 + k][ox];
            float a1 = sH[1][oy0 + k][ox];
            float a2 = sH[2][oy0 + k][ox];
            float a3 = sH[3][oy0 + k][ox];
            float a4 = sH[4][oy0 + k][ox];
            #pragma unroll
            for (int j = 0; j < RY; ++j) {
                int kk = k - j;
                if (kk >= 0 && kk < WSZ) {
                    float wv = wt.w[kk];
                    mu1[j] += wv * a0;
                    mu2[j] += wv * a1;
                    spp[j] += wv * a2;
                    stt[j] += wv * a3;
                    spt[j] += wv * a4;
                }
            }
        }
        #pragma unroll
        for (int j = 0; j < RY; ++j) {
            float m1 = mu1[j], m2 = mu2[j];
            float mu1s = m1 * m1;
            float mu2s = m2 * m2;
            float m12  = m1 * m2;
            float num = (2.f * m12 + C1v) * (2.f * (spt[j] - m12) + C2v);
            float den = (mu1s + mu2s + C1v) * ((spp[j] - mu1s) + (stt[j] - mu2s) + C2v);
            ssim_acc += num * __builtin_amdgcn_rcpf(den);
        }
    }

    // ================= block reduction -> global double atomics =============
    #pragma unroll
    for (int off = 32; off > 0; off >>= 1) {
        ssim_acc += __shfl_down(ssim_acc, off, 64);
        l1_acc   += __shfl_down(l1_acc,   off, 64);
    }
    __shared__ float red[2][4];
    int lane = tid & 63;
    int wid  = tid >> 6;
    if (lane == 0) { red[0][wid] = ssim_acc; red[1][wid] = l1_acc; }
    __syncthreads();
    if (tid == 0) {
        float s = red[0][0] + red[0][1] + red[0][2] + red[0][3];
        float l = red[1][0] + red[1][1] + red[1][2] + red[1][3];
        atomicAdd(&acc[0], (double)s);
        atomicAdd(&acc[1], (double)l);
    }
}

__global__ void finalize_kernel(const double* __restrict__ acc,
                                float* __restrict__ out, double invN)
{
    double ssim_mean = acc[0] * invN;
    double l1_mean   = acc[1] * invN;
    out[0] = (float)(0.8 * l1_mean + 0.2 * (1.0 - ssim_mean));
}

extern "C" void kernel_launch(void* const* d_in, const int* in_sizes, int n_in,
                              void* d_out, int out_size, void* d_ws, size_t ws_size,
                              hipStream_t stream)
{
    const float* pred = (const float*)d_in[0];
    const float* targ = (const float*)d_in[1];
    float* out = (float*)d_out;
    double* acc = (double*)d_ws;

    const int C = 3, H = 2160, W = 3840;

    hipMemsetAsync(acc, 0, 2 * sizeof(double), stream);

    W11 wt;
    double g[WSZ], s = 0.0;
    for (int i = 0; i < WSZ; ++i) {
        double d = (double)i - (WSZ / 2);
        g[i] = exp(-(d * d) / (2.0 * 1.5 * 1.5));
        s += g[i];
    }
    for (int i = 0; i < WSZ; ++i) wt.w[i] = (float)(g[i] / s);

    dim3 grid(W / TX, H / TY, C);   // 120 x 45 x 3
    ssim_l1_kernel<<<grid, 256, 0, stream>>>(pred, targ, wt, acc);

    double invN = 1.0 / ((double)C * (double)H * (double)W);
    finalize_kernel<<<1, 1, 0, stream>>>(acc, out, invN);
}